// Round 17
// baseline (617.804 us; speedup 1.0000x reference)
//
#include <hip/hip_runtime.h>
#include <hip/hip_fp16.h>

#define N_NODES 40000
#define N_EDGES 640000
#define DIM 128
#define N_GRAPHS 64
#define BN_EPS 1e-5f
#define AGG_BLOCKS 512           // x 1024 threads = 8192 waves
#define SCAN_NB 40   // ceil(40000/1024)
#define NTILES 625   // 64-row tiles
#define GEMM_BLOCKS 256
#define WTP 136      // padded k-stride for Wt / A tiles (halves)
#define FILL_NB ((N_EDGES + 255) / 256)           // 2500
#define PREPW_NB ((3 * DIM * DIM + 255) / 256)    // 192

typedef _Float16 f16x8 __attribute__((ext_vector_type(8)));
typedef float    f32x4 __attribute__((ext_vector_type(4)));

// ---------------- CSR build ----------------
__global__ __launch_bounds__(256) void k_count_edges(const int* __restrict__ ei, int* __restrict__ cnt,
                                                     int* __restrict__ rank) {
    int e = blockIdx.x * 256 + threadIdx.x;
    if (e < N_EDGES) rank[e] = atomicAdd(&cnt[ei[N_EDGES + e]], 1);
}

__global__ __launch_bounds__(1024) void k_scan_blk(const int* __restrict__ cnt, int* __restrict__ off,
                                                   int* __restrict__ blocksum) {
    __shared__ int sums[1024];
    int i = blockIdx.x * 1024 + threadIdx.x;
    int v = (i < N_NODES) ? cnt[i] : 0;
    sums[threadIdx.x] = v;
    __syncthreads();
    for (int d = 1; d < 1024; d <<= 1) {
        int t = (threadIdx.x >= d) ? sums[threadIdx.x - d] : 0;
        __syncthreads();
        sums[threadIdx.x] += t;
        __syncthreads();
    }
    if (i < N_NODES) off[i] = sums[threadIdx.x] - v;        // exclusive within block
    if (threadIdx.x == 1023) blocksum[blockIdx.x] = sums[1023];
}

__global__ __launch_bounds__(1024) void k_scan_fix(const int* __restrict__ cnt, const int* __restrict__ blocksum,
                                                   int* __restrict__ off, float* __restrict__ dinv,
                                                   const int* __restrict__ batch, int* __restrict__ goff) {
    __shared__ int bo[2];
    if (threadIdx.x == 0) {
        int run = 0, tot = 0;
        for (int b = 0; b < SCAN_NB; ++b) {
            int v = blocksum[b];
            if (b < (int)blockIdx.x) run += v;
            tot += v;
        }
        bo[0] = run; bo[1] = tot;
    }
    __syncthreads();
    int i = blockIdx.x * 1024 + threadIdx.x;
    if (i < N_NODES) {
        off[i] += bo[0];
        dinv[i] = rsqrtf((float)(cnt[i] + 1));              // +1 self loop, always > 0
        int b = batch[i];
        int bp = (i == 0) ? -1 : batch[i - 1];
        for (int g = bp + 1; g <= b; ++g) goff[g] = i;      // rare divergence
        if (i == N_NODES - 1)
            for (int g = b + 1; g <= N_GRAPHS; ++g) goff[g] = N_NODES;
    }
    if (i == 0) off[N_NODES] = bo[1];
}

// fill (blocks < FILL_NB) + W prep (blocks >= FILL_NB) merged in one dispatch
__global__ __launch_bounds__(256) void k_fill_prepw(const int* __restrict__ ei, const int* __restrict__ rank,
                                                    const int* __restrict__ off, int* __restrict__ elist,
                                                    const float* __restrict__ Ws, __half* __restrict__ wt) {
    if (blockIdx.x < FILL_NB) {
        int e = blockIdx.x * 256 + threadIdx.x;
        if (e < N_EDGES) {
            int s = ei[e];                 // src row
            int d = ei[N_EDGES + e];       // dst row
            elist[off[d] + rank[e]] = s;   // 4B scatter; coef recomputed in agg
        }
    } else {
        int idx = (blockIdx.x - FILL_NB) * 256 + threadIdx.x;   // 3*128*128
        if (idx < 3 * DIM * DIM) {
            int l = idx >> 14;
            int rem = idx & 16383;
            int k = rem >> 7;         // row of W
            int c = rem & 127;        // col of W
            float w = Ws[(size_t)l * DIM * DIM + k * DIM + c];
            __half hi = __float2half(w);
            __half lo = __float2half(w - __half2float(hi));
            size_t base = (size_t)l * 2 * DIM * WTP;
            wt[base + (size_t)c * WTP + k] = hi;
            wt[base + (size_t)DIM * WTP + (size_t)c * WTP + k] = lo;
        }
    }
}

// ---------------- GEMM building blocks ----------------
__device__ __forceinline__ void stage_a_f32(const float* __restrict__ in, __half* Al, long row0, int t) {
    for (int i = t; i < 2048; i += 256) {   // 64 rows x 32 float4
        int r = i >> 5, k4 = i & 31;
        float4 v = ((const float4*)(in + (row0 + r) * DIM))[k4];
        __half2* d = (__half2*)&Al[r * WTP + k4 * 4];
        d[0] = __floats2half2_rn(v.x, v.y);
        d[1] = __floats2half2_rn(v.z, v.w);
    }
}

__device__ __forceinline__ void stage_a_f16(const __half* __restrict__ in, const float* __restrict__ ac,
                                            __half* Al, long row0, int t) {
    for (int i = t; i < 1024; i += 256) {   // 64 rows x 16 chunks of 8 halves
        int r = i >> 4, k8 = i & 15;
        const __half2* src = (const __half2*)(in + (row0 + r) * DIM + k8 * 8);
        int k = k8 * 8;
        float2 f0 = __half22float2(src[0]);
        float2 f1 = __half22float2(src[1]);
        float2 f2 = __half22float2(src[2]);
        float2 f3 = __half22float2(src[3]);
        f0.x = fmaf(ac[k + 0], f0.x, ac[DIM + k + 0]); f0.y = fmaf(ac[k + 1], f0.y, ac[DIM + k + 1]);
        f1.x = fmaf(ac[k + 2], f1.x, ac[DIM + k + 2]); f1.y = fmaf(ac[k + 3], f1.y, ac[DIM + k + 3]);
        f2.x = fmaf(ac[k + 4], f2.x, ac[DIM + k + 4]); f2.y = fmaf(ac[k + 5], f2.y, ac[DIM + k + 5]);
        f3.x = fmaf(ac[k + 6], f3.x, ac[DIM + k + 6]); f3.y = fmaf(ac[k + 7], f3.y, ac[DIM + k + 7]);
        __half2* d = (__half2*)&Al[r * WTP + k];
        d[0] = __floats2half2_rn(f0.x, f0.y);
        d[1] = __floats2half2_rn(f1.x, f1.y);
        d[2] = __floats2half2_rn(f2.x, f2.y);
        d[3] = __floats2half2_rn(f3.x, f3.y);
    }
}

__device__ __forceinline__ void compute_tile(const __half* Wl2, const __half* Al,
                                             const float* __restrict__ bias, __half* __restrict__ out16,
                                             int t, long row0) {
    int w = t >> 6;            // wave 0..3 -> rows w*16..w*16+15
    int l = t & 63;
    int lr = l & 15;           // A row-in-tile / B col-in-tile / D col
    int lk = (l >> 4) * 8;     // k sub-block

    f32x4 acc[8];
#pragma unroll
    for (int i = 0; i < 8; ++i) acc[i] = (f32x4)(0.f);

#pragma unroll
    for (int ks = 0; ks < 4; ++ks) {
        f16x8 a = *(const f16x8*)&Al[(w * 16 + lr) * WTP + ks * 32 + lk];
#pragma unroll
        for (int tile = 0; tile < 8; ++tile) {
            f16x8 bh = *(const f16x8*)&Wl2[(tile * 16 + lr) * WTP + ks * 32 + lk];
            f16x8 bl = *(const f16x8*)&Wl2[DIM * WTP + (tile * 16 + lr) * WTP + ks * 32 + lk];
            acc[tile] = __builtin_amdgcn_mfma_f32_16x16x32_f16(a, bh, acc[tile], 0, 0, 0);
            acc[tile] = __builtin_amdgcn_mfma_f32_16x16x32_f16(a, bl, acc[tile], 0, 0, 0);
        }
    }

    long orow = row0 + w * 16 + (l >> 4) * 4;   // D: col=l&15, row=(l>>4)*4+i
#pragma unroll
    for (int tile = 0; tile < 8; ++tile) {
        int col = tile * 16 + lr;
        float b = bias[col];
#pragma unroll
        for (int i = 0; i < 4; ++i)
            out16[(orow + i) * DIM + col] = __float2half(acc[tile][i] + b);
    }
}

// persistent-block GEMM: W staged once/block; A-tile double-buffered.
__global__ __launch_bounds__(256) void k_gemm_f32(const float* __restrict__ in, const __half* __restrict__ wt2,
                                                  const float* __restrict__ bias, __half* __restrict__ out16) {
    __shared__ __half Wl2[2 * DIM * WTP];
    __shared__ __half Al[2][64 * WTP];
    int t = threadIdx.x;
    {
        const float4* src = (const float4*)wt2;
        float4* dst = (float4*)Wl2;
        for (int i = t; i < 4352; i += 256) dst[i] = src[i];
    }
    int tile = blockIdx.x;
    stage_a_f32(in, Al[0], (long)tile * 64, t);
    __syncthreads();
    int buf = 0;
    while (tile < NTILES) {
        int next = tile + GEMM_BLOCKS;
        if (next < NTILES) stage_a_f32(in, Al[buf ^ 1], (long)next * 64, t);
        compute_tile(Wl2, Al[buf], bias, out16, t, (long)tile * 64);
        __syncthreads();
        buf ^= 1;
        tile = next;
    }
}

__global__ __launch_bounds__(256) void k_gemm_f16(const __half* __restrict__ in, const __half* __restrict__ wt2,
                                                  const float* __restrict__ bias, const float* __restrict__ ac,
                                                  __half* __restrict__ out16) {
    __shared__ __half Wl2[2 * DIM * WTP];
    __shared__ __half Al[2][64 * WTP];
    int t = threadIdx.x;
    {
        const float4* src = (const float4*)wt2;
        float4* dst = (float4*)Wl2;
        for (int i = t; i < 4352; i += 256) dst[i] = src[i];
    }
    int tile = blockIdx.x;
    stage_a_f16(in, ac, Al[0], (long)tile * 64, t);
    __syncthreads();
    int buf = 0;
    while (tile < NTILES) {
        int next = tile + GEMM_BLOCKS;
        if (next < NTILES) stage_a_f16(in, ac, Al[buf ^ 1], (long)next * 64, t);
        compute_tile(Wl2, Al[buf], bias, out16, t, (long)tile * 64);
        __syncthreads();
        buf ^= 1;
        tile = next;
    }
}

// ---------------- Aggregation + ReLU + BN stats (fused, last-block) -------
__global__ __launch_bounds__(1024) void k_agg(const __half* __restrict__ h16, const int* __restrict__ off,
                                              const int* __restrict__ elist,
                                              const float* __restrict__ dinv, __half* __restrict__ hout,
                                              float* __restrict__ partials, int* __restrict__ done,
                                              const float* __restrict__ gamma, const float* __restrict__ beta,
                                              float* __restrict__ ac) {
    __shared__ float colacc[256];
    if (threadIdx.x < 256) colacc[threadIdx.x] = 0.f;
    __syncthreads();

    const __half2* rows = (const __half2*)h16;   // 64 half2 per row
    int lane = threadIdx.x & 63;
    int wid = (blockIdx.x * 1024 + threadIdx.x) >> 6;
    const int NW = AGG_BLOCKS * 16;
    float s0 = 0.f, s1 = 0.f, q0 = 0.f, q1 = 0.f;

    for (int i = wid; i < N_NODES; i += NW) {
        float di = dinv[i];
        float selfc = di * di;
        float2 rv = __half22float2(rows[(long)i * 64 + lane]);
        float a0 = rv.x * selfc, a1 = rv.y * selfc;
        int e  = off[i];
        int e1 = off[i + 1];
#pragma unroll 4
        for (; e < e1; ++e) {
            int s = elist[e];
            float c = dinv[s] * di;
            float2 r = __half22float2(rows[(long)s * 64 + lane]);
            a0 = fmaf(r.x, c, a0);
            a1 = fmaf(r.y, c, a1);
        }
        a0 = fmaxf(a0, 0.f);
        a1 = fmaxf(a1, 0.f);
        ((__half2*)(hout + (long)i * DIM))[lane] = __floats2half2_rn(a0, a1);
        s0 += a0; q0 += a0 * a0; s1 += a1; q1 += a1 * a1;
    }

    // partials layout: [0..127] col sums, [128..255] col sumsq (true col idx)
    atomicAdd(&colacc[2 * lane],           s0);
    atomicAdd(&colacc[2 * lane + 1],       s1);
    atomicAdd(&colacc[128 + 2 * lane],     q0);
    atomicAdd(&colacc[128 + 2 * lane + 1], q1);
    __syncthreads();
    if (threadIdx.x < 256)
        partials[(long)blockIdx.x * 256 + threadIdx.x] = colacc[threadIdx.x];

    // last finished block computes BN stats -> ac (fixed-order sum)
    __threadfence();
    __shared__ int isLast;
    if (threadIdx.x == 0) isLast = (atomicAdd(done, 1) == AGG_BLOCKS - 1) ? 1 : 0;
    __syncthreads();
    if (!isLast) return;

    __shared__ float ls[1024], lq[1024];
    int d = threadIdx.x & 127;
    int seg = threadIdx.x >> 7;                    // 8 segments
    float s = 0.f, q = 0.f;
    for (int b = seg; b < AGG_BLOCKS; b += 8) {    // 64 iters, fixed order
        s += partials[b * 256 + d];
        q += partials[b * 256 + 128 + d];
    }
    ls[threadIdx.x] = s; lq[threadIdx.x] = q;
    __syncthreads();
    for (int o = 512; o >= 128; o >>= 1) {
        if (threadIdx.x < o) {
            ls[threadIdx.x] += ls[threadIdx.x + o];
            lq[threadIdx.x] += lq[threadIdx.x + o];
        }
        __syncthreads();
    }
    if (threadIdx.x < 128) {
        s = ls[threadIdx.x]; q = lq[threadIdx.x];
        float mean = s * (1.f / N_NODES);
        float var  = q * (1.f / N_NODES) - mean * mean;
        float a = gamma[d] * rsqrtf(var + BN_EPS);
        ac[d] = a;
        ac[DIM + d] = fmaf(-mean, a, beta[d]);
        if (threadIdx.x == 0) *done = 0;           // self-restore for next layer
    }
}

// ---------------- Pool + final MLP fused (per graph) ----------------
__global__ __launch_bounds__(1024) void k_poolmlp(const __half* __restrict__ h, const float* __restrict__ ac,
                                                  const int* __restrict__ goff,
                                                  const float* __restrict__ w1, const float* __restrict__ b1,
                                                  const float* __restrict__ w2, const float* __restrict__ b2,
                                                  float* __restrict__ out) {
    __shared__ float2 red[1024];
    __shared__ float pl[DIM];
    int g = blockIdx.x;
    int d2 = threadIdx.x & 63;                     // col pair
    int seg = threadIdx.x >> 6;                    // 16 segments
    int r0 = goff[g], r1 = goff[g + 1];
    const __half2* rows = (const __half2*)h;
    float s0 = 0.f, s1 = 0.f;
    for (int r = r0 + seg; r < r1; r += 16) {
        float2 v = __half22float2(rows[(long)r * 64 + d2]);
        s0 += v.x; s1 += v.y;
    }
    red[threadIdx.x] = make_float2(s0, s1);
    __syncthreads();
    for (int off = 512; off >= 64; off >>= 1) {
        if (threadIdx.x < off) {
            red[threadIdx.x].x += red[threadIdx.x + off].x;
            red[threadIdx.x].y += red[threadIdx.x + off].y;
        }
        __syncthreads();
    }
    if (threadIdx.x < 64) {
        float2 s = red[threadIdx.x];
        int n = r1 - r0;
        float fn = (float)n;
        float denom = (float)(n > 0 ? n : 1);
        int d = 2 * threadIdx.x;
        pl[d]     = (ac[d] * s.x     + ac[DIM + d] * fn)     / denom;
        pl[d + 1] = (ac[d + 1] * s.y + ac[DIM + d + 1] * fn) / denom;
    }
    __syncthreads();
    if (threadIdx.x < 64) {
        int j = threadIdx.x;
        float hh = b1[j];
#pragma unroll
        for (int k = 0; k < DIM; ++k) hh = fmaf(pl[k], w1[k * 64 + j], hh);
        hh = fmaxf(hh, 0.f);
        float v = hh * w2[j];
#pragma unroll
        for (int o = 32; o > 0; o >>= 1) v += __shfl_down(v, o);
        if (j == 0) out[g] = v + b2[0];
    }
}

extern "C" void kernel_launch(void* const* d_in, const int* in_sizes, int n_in,
                              void* d_out, int out_size, void* d_ws, size_t ws_size,
                              hipStream_t stream) {
    const float* x      = (const float*)d_in[0];
    const int*   ei     = (const int*)d_in[1];
    const int*   batch  = (const int*)d_in[2];
    const float* Ws     = (const float*)d_in[3];
    const float* bs     = (const float*)d_in[4];
    const float* gammas = (const float*)d_in[5];
    const float* betas  = (const float*)d_in[6];
    const float* w1     = (const float*)d_in[7];
    const float* b1     = (const float*)d_in[8];
    const float* w2     = (const float*)d_in[9];
    const float* b2     = (const float*)d_in[10];
    float* out = (float*)d_out;

    char* p = (char*)d_ws;
    auto alloc = [&](size_t bytes) { void* r = (void*)p; p += (bytes + 255) & ~(size_t)255; return r; };
    int*    cnt      = (int*)alloc((size_t)N_NODES * 4);
    int*    off      = (int*)alloc((size_t)(N_NODES + 1) * 4);
    int*    rank     = (int*)alloc((size_t)N_EDGES * 4);
    int*    goff     = (int*)alloc((size_t)(N_GRAPHS + 1) * 4);
    int*    blocksum = (int*)alloc((size_t)(SCAN_NB + 1) * 4);
    int*    done     = (int*)alloc(256);
    int*    elist    = (int*)alloc((size_t)N_EDGES * 4);
    float*  dinv     = (float*)alloc((size_t)N_NODES * 4);
    __half* wt       = (__half*)alloc((size_t)3 * 2 * DIM * WTP * 2);
    __half* h16      = (__half*)alloc((size_t)N_NODES * DIM * 2);
    __half* v16      = (__half*)alloc((size_t)N_NODES * DIM * 2);
    float*  parts    = (float*)alloc((size_t)AGG_BLOCKS * 256 * 4);
    float*  ac       = (float*)alloc(256 * 4);

    hipMemsetAsync(cnt, 0, (size_t)N_NODES * 4, stream);
    hipMemsetAsync(done, 0, 256, stream);

    k_count_edges<<<(N_EDGES + 255) / 256, 256, 0, stream>>>(ei, cnt, rank);
    k_scan_blk<<<SCAN_NB, 1024, 0, stream>>>(cnt, off, blocksum);
    k_scan_fix<<<SCAN_NB, 1024, 0, stream>>>(cnt, blocksum, off, dinv, batch, goff);
    k_fill_prepw<<<FILL_NB + PREPW_NB, 256, 0, stream>>>(ei, rank, off, elist, Ws, wt);

    for (int l = 0; l < 3; ++l) {
        if (l == 0)
            k_gemm_f32<<<GEMM_BLOCKS, 256, 0, stream>>>(x, wt, bs, h16);
        else
            k_gemm_f16<<<GEMM_BLOCKS, 256, 0, stream>>>(v16, wt + (size_t)l * 2 * DIM * WTP,
                                                        bs + (size_t)l * DIM, ac, h16);
        k_agg<<<AGG_BLOCKS, 1024, 0, stream>>>(h16, off, elist, dinv, v16, parts, done,
                                               gammas + (size_t)l * DIM, betas + (size_t)l * DIM, ac);
    }
    k_poolmlp<<<N_GRAPHS, 1024, 0, stream>>>(v16, ac, goff, w1, b1, w2, b2, out);
}

// Round 18
// 237.084 us; speedup vs baseline: 2.6058x; 2.6058x over previous
//
#include <hip/hip_runtime.h>
#include <hip/hip_fp16.h>

#define N_NODES 40000
#define N_EDGES 640000
#define DIM 128
#define N_GRAPHS 64
#define BN_EPS 1e-5f
#define AGG_BLOCKS 512           // x 1024 threads = 8192 waves (same as before)
#define SCAN_NB 40   // ceil(40000/1024)
#define NTILES 625   // 64-row tiles
#define GEMM_BLOCKS 256
#define WTP 136      // padded k-stride for Wt / A tiles (halves)
#define FILL_NB ((N_EDGES + 255) / 256)           // 2500
#define PREPW_NB ((3 * DIM * DIM + 255) / 256)    // 192

typedef _Float16 f16x8 __attribute__((ext_vector_type(8)));
typedef float    f32x4 __attribute__((ext_vector_type(4)));

// ---------------- CSR build ----------------
__global__ __launch_bounds__(256) void k_count_edges(const int* __restrict__ ei, int* __restrict__ cnt,
                                                     int* __restrict__ rank) {
    int e = blockIdx.x * 256 + threadIdx.x;
    if (e < N_EDGES) rank[e] = atomicAdd(&cnt[ei[N_EDGES + e]], 1);
}

__global__ __launch_bounds__(1024) void k_scan_blk(const int* __restrict__ cnt, int* __restrict__ off,
                                                   int* __restrict__ blocksum) {
    __shared__ int sums[1024];
    int i = blockIdx.x * 1024 + threadIdx.x;
    int v = (i < N_NODES) ? cnt[i] : 0;
    sums[threadIdx.x] = v;
    __syncthreads();
    for (int d = 1; d < 1024; d <<= 1) {
        int t = (threadIdx.x >= d) ? sums[threadIdx.x - d] : 0;
        __syncthreads();
        sums[threadIdx.x] += t;
        __syncthreads();
    }
    if (i < N_NODES) off[i] = sums[threadIdx.x] - v;        // exclusive within block
    if (threadIdx.x == 1023) blocksum[blockIdx.x] = sums[1023];
}

__global__ __launch_bounds__(1024) void k_scan_fix(const int* __restrict__ cnt, const int* __restrict__ blocksum,
                                                   int* __restrict__ off, float* __restrict__ dinv,
                                                   const int* __restrict__ batch, int* __restrict__ goff) {
    __shared__ int bo[2];
    if (threadIdx.x == 0) {
        int run = 0, tot = 0;
        for (int b = 0; b < SCAN_NB; ++b) {
            int v = blocksum[b];
            if (b < (int)blockIdx.x) run += v;
            tot += v;
        }
        bo[0] = run; bo[1] = tot;
    }
    __syncthreads();
    int i = blockIdx.x * 1024 + threadIdx.x;
    if (i < N_NODES) {
        off[i] += bo[0];
        dinv[i] = rsqrtf((float)(cnt[i] + 1));              // +1 self loop, always > 0
        int b = batch[i];
        int bp = (i == 0) ? -1 : batch[i - 1];
        for (int g = bp + 1; g <= b; ++g) goff[g] = i;      // rare divergence
        if (i == N_NODES - 1)
            for (int g = b + 1; g <= N_GRAPHS; ++g) goff[g] = N_NODES;
    }
    if (i == 0) off[N_NODES] = bo[1];
}

// fill (blocks < FILL_NB) + W prep (blocks >= FILL_NB) merged in one dispatch
__global__ __launch_bounds__(256) void k_fill_prepw(const int* __restrict__ ei, const int* __restrict__ rank,
                                                    const int* __restrict__ off, int* __restrict__ elist,
                                                    const float* __restrict__ Ws, __half* __restrict__ wt) {
    if (blockIdx.x < FILL_NB) {
        int e = blockIdx.x * 256 + threadIdx.x;
        if (e < N_EDGES) {
            int s = ei[e];                 // src row
            int d = ei[N_EDGES + e];       // dst row
            elist[off[d] + rank[e]] = s;   // 4B scatter; coef recomputed in agg
        }
    } else {
        int idx = (blockIdx.x - FILL_NB) * 256 + threadIdx.x;   // 3*128*128
        if (idx < 3 * DIM * DIM) {
            int l = idx >> 14;
            int rem = idx & 16383;
            int k = rem >> 7;         // row of W
            int c = rem & 127;        // col of W
            float w = Ws[(size_t)l * DIM * DIM + k * DIM + c];
            __half hi = __float2half(w);
            __half lo = __float2half(w - __half2float(hi));
            size_t base = (size_t)l * 2 * DIM * WTP;
            wt[base + (size_t)c * WTP + k] = hi;
            wt[base + (size_t)DIM * WTP + (size_t)c * WTP + k] = lo;
        }
    }
}

// ---------------- GEMM building blocks ----------------
__device__ __forceinline__ void stage_a_f32(const float* __restrict__ in, __half* Al, long row0, int t) {
    for (int i = t; i < 2048; i += 256) {   // 64 rows x 32 float4
        int r = i >> 5, k4 = i & 31;
        float4 v = ((const float4*)(in + (row0 + r) * DIM))[k4];
        __half2* d = (__half2*)&Al[r * WTP + k4 * 4];
        d[0] = __floats2half2_rn(v.x, v.y);
        d[1] = __floats2half2_rn(v.z, v.w);
    }
}

__device__ __forceinline__ void stage_a_f16(const __half* __restrict__ in, const float* __restrict__ ac,
                                            __half* Al, long row0, int t) {
    for (int i = t; i < 1024; i += 256) {   // 64 rows x 16 chunks of 8 halves
        int r = i >> 4, k8 = i & 15;
        const __half2* src = (const __half2*)(in + (row0 + r) * DIM + k8 * 8);
        int k = k8 * 8;
        float2 f0 = __half22float2(src[0]);
        float2 f1 = __half22float2(src[1]);
        float2 f2 = __half22float2(src[2]);
        float2 f3 = __half22float2(src[3]);
        f0.x = fmaf(ac[k + 0], f0.x, ac[DIM + k + 0]); f0.y = fmaf(ac[k + 1], f0.y, ac[DIM + k + 1]);
        f1.x = fmaf(ac[k + 2], f1.x, ac[DIM + k + 2]); f1.y = fmaf(ac[k + 3], f1.y, ac[DIM + k + 3]);
        f2.x = fmaf(ac[k + 4], f2.x, ac[DIM + k + 4]); f2.y = fmaf(ac[k + 5], f2.y, ac[DIM + k + 5]);
        f3.x = fmaf(ac[k + 6], f3.x, ac[DIM + k + 6]); f3.y = fmaf(ac[k + 7], f3.y, ac[DIM + k + 7]);
        __half2* d = (__half2*)&Al[r * WTP + k];
        d[0] = __floats2half2_rn(f0.x, f0.y);
        d[1] = __floats2half2_rn(f1.x, f1.y);
        d[2] = __floats2half2_rn(f2.x, f2.y);
        d[3] = __floats2half2_rn(f3.x, f3.y);
    }
}

__device__ __forceinline__ void compute_tile(const __half* Wl2, const __half* Al,
                                             const float* __restrict__ bias, __half* __restrict__ out16,
                                             int t, long row0) {
    int w = t >> 6;            // wave 0..3 -> rows w*16..w*16+15
    int l = t & 63;
    int lr = l & 15;           // A row-in-tile / B col-in-tile / D col
    int lk = (l >> 4) * 8;     // k sub-block

    f32x4 acc[8];
#pragma unroll
    for (int i = 0; i < 8; ++i) acc[i] = (f32x4)(0.f);

#pragma unroll
    for (int ks = 0; ks < 4; ++ks) {
        f16x8 a = *(const f16x8*)&Al[(w * 16 + lr) * WTP + ks * 32 + lk];
#pragma unroll
        for (int tile = 0; tile < 8; ++tile) {
            f16x8 bh = *(const f16x8*)&Wl2[(tile * 16 + lr) * WTP + ks * 32 + lk];
            f16x8 bl = *(const f16x8*)&Wl2[DIM * WTP + (tile * 16 + lr) * WTP + ks * 32 + lk];
            acc[tile] = __builtin_amdgcn_mfma_f32_16x16x32_f16(a, bh, acc[tile], 0, 0, 0);
            acc[tile] = __builtin_amdgcn_mfma_f32_16x16x32_f16(a, bl, acc[tile], 0, 0, 0);
        }
    }

    long orow = row0 + w * 16 + (l >> 4) * 4;   // D: col=l&15, row=(l>>4)*4+i
#pragma unroll
    for (int tile = 0; tile < 8; ++tile) {
        int col = tile * 16 + lr;
        float b = bias[col];
#pragma unroll
        for (int i = 0; i < 4; ++i)
            out16[(orow + i) * DIM + col] = __float2half(acc[tile][i] + b);
    }
}

// persistent-block GEMM: W staged once/block; A-tile double-buffered.
__global__ __launch_bounds__(256) void k_gemm_f32(const float* __restrict__ in, const __half* __restrict__ wt2,
                                                  const float* __restrict__ bias, __half* __restrict__ out16) {
    __shared__ __half Wl2[2 * DIM * WTP];
    __shared__ __half Al[2][64 * WTP];
    int t = threadIdx.x;
    {
        const float4* src = (const float4*)wt2;
        float4* dst = (float4*)Wl2;
        for (int i = t; i < 4352; i += 256) dst[i] = src[i];
    }
    int tile = blockIdx.x;
    stage_a_f32(in, Al[0], (long)tile * 64, t);
    __syncthreads();
    int buf = 0;
    while (tile < NTILES) {
        int next = tile + GEMM_BLOCKS;
        if (next < NTILES) stage_a_f32(in, Al[buf ^ 1], (long)next * 64, t);
        compute_tile(Wl2, Al[buf], bias, out16, t, (long)tile * 64);
        __syncthreads();
        buf ^= 1;
        tile = next;
    }
}

__global__ __launch_bounds__(256) void k_gemm_f16(const __half* __restrict__ in, const __half* __restrict__ wt2,
                                                  const float* __restrict__ bias, const float* __restrict__ ac,
                                                  __half* __restrict__ out16) {
    __shared__ __half Wl2[2 * DIM * WTP];
    __shared__ __half Al[2][64 * WTP];
    int t = threadIdx.x;
    {
        const float4* src = (const float4*)wt2;
        float4* dst = (float4*)Wl2;
        for (int i = t; i < 4352; i += 256) dst[i] = src[i];
    }
    int tile = blockIdx.x;
    stage_a_f16(in, ac, Al[0], (long)tile * 64, t);
    __syncthreads();
    int buf = 0;
    while (tile < NTILES) {
        int next = tile + GEMM_BLOCKS;
        if (next < NTILES) stage_a_f16(in, ac, Al[buf ^ 1], (long)next * 64, t);
        compute_tile(Wl2, Al[buf], bias, out16, t, (long)tile * 64);
        __syncthreads();
        buf ^= 1;
        tile = next;
    }
}

// ---------------- Aggregation + ReLU + BN partial stats -------------------
// 512 blocks x 1024 threads (16 waves) = 8192 waves. NO device fences here:
// the gather depends on L2 residency (R17 lesson: threadfence = 5x slowdown).
__global__ __launch_bounds__(1024) void k_agg(const __half* __restrict__ h16, const int* __restrict__ off,
                                              const int* __restrict__ elist,
                                              const float* __restrict__ dinv, __half* __restrict__ hout,
                                              float* __restrict__ partials) {
    __shared__ float colacc[256];
    if (threadIdx.x < 256) colacc[threadIdx.x] = 0.f;
    __syncthreads();

    const __half2* rows = (const __half2*)h16;   // 64 half2 per row
    int lane = threadIdx.x & 63;
    int wid = (blockIdx.x * 1024 + threadIdx.x) >> 6;
    const int NW = AGG_BLOCKS * 16;
    float s0 = 0.f, s1 = 0.f, q0 = 0.f, q1 = 0.f;

    for (int i = wid; i < N_NODES; i += NW) {
        float di = dinv[i];
        float selfc = di * di;
        float2 rv = __half22float2(rows[(long)i * 64 + lane]);
        float a0 = rv.x * selfc, a1 = rv.y * selfc;
        int e  = off[i];
        int e1 = off[i + 1];
#pragma unroll 4
        for (; e < e1; ++e) {
            int s = elist[e];
            float c = dinv[s] * di;
            float2 r = __half22float2(rows[(long)s * 64 + lane]);
            a0 = fmaf(r.x, c, a0);
            a1 = fmaf(r.y, c, a1);
        }
        a0 = fmaxf(a0, 0.f);
        a1 = fmaxf(a1, 0.f);
        ((__half2*)(hout + (long)i * DIM))[lane] = __floats2half2_rn(a0, a1);
        s0 += a0; q0 += a0 * a0; s1 += a1; q1 += a1 * a1;
    }

    // partials layout: [0..127] col sums, [128..255] col sumsq (true col idx)
    atomicAdd(&colacc[2 * lane],           s0);
    atomicAdd(&colacc[2 * lane + 1],       s1);
    atomicAdd(&colacc[128 + 2 * lane],     q0);
    atomicAdd(&colacc[128 + 2 * lane + 1], q1);
    __syncthreads();
    if (threadIdx.x < 256)
        partials[(long)blockIdx.x * 256 + threadIdx.x] = colacc[threadIdx.x];
}

// ---------------- BN stats -> affine a,c (8 blocks x 16 cols) ----------------
__global__ __launch_bounds__(1024) void k_stats(const float* __restrict__ partials,
                                                const float* __restrict__ gamma, const float* __restrict__ beta,
                                                float* __restrict__ ac) {
    __shared__ float ls[1024], lq[1024];
    int dd = threadIdx.x & 15;
    int seg = threadIdx.x >> 4;                    // 64 segments
    int d = blockIdx.x * 16 + dd;
    float s = 0.f, q = 0.f;
    for (int b = seg; b < AGG_BLOCKS; b += 64) {   // 8 iters
        s += partials[b * 256 + d];
        q += partials[b * 256 + 128 + d];
    }
    ls[threadIdx.x] = s; lq[threadIdx.x] = q;
    __syncthreads();
    for (int off = 512; off >= 16; off >>= 1) {
        if (threadIdx.x < off) {
            ls[threadIdx.x] += ls[threadIdx.x + off];
            lq[threadIdx.x] += lq[threadIdx.x + off];
        }
        __syncthreads();
    }
    if (threadIdx.x < 16) {
        s = ls[threadIdx.x]; q = lq[threadIdx.x];
        float mean = s * (1.f / N_NODES);
        float var  = q * (1.f / N_NODES) - mean * mean;
        float a = gamma[d] * rsqrtf(var + BN_EPS);
        ac[d] = a;
        ac[DIM + d] = fmaf(-mean, a, beta[d]);
    }
}

// ---------------- Pool + final MLP fused (per graph) ----------------
__global__ __launch_bounds__(1024) void k_poolmlp(const __half* __restrict__ h, const float* __restrict__ ac,
                                                  const int* __restrict__ goff,
                                                  const float* __restrict__ w1, const float* __restrict__ b1,
                                                  const float* __restrict__ w2, const float* __restrict__ b2,
                                                  float* __restrict__ out) {
    __shared__ float2 red[1024];
    __shared__ float pl[DIM];
    int g = blockIdx.x;
    int d2 = threadIdx.x & 63;                     // col pair
    int seg = threadIdx.x >> 6;                    // 16 segments
    int r0 = goff[g], r1 = goff[g + 1];
    const __half2* rows = (const __half2*)h;
    float s0 = 0.f, s1 = 0.f;
    for (int r = r0 + seg; r < r1; r += 16) {
        float2 v = __half22float2(rows[(long)r * 64 + d2]);
        s0 += v.x; s1 += v.y;
    }
    red[threadIdx.x] = make_float2(s0, s1);
    __syncthreads();
    for (int off = 512; off >= 64; off >>= 1) {
        if (threadIdx.x < off) {
            red[threadIdx.x].x += red[threadIdx.x + off].x;
            red[threadIdx.x].y += red[threadIdx.x + off].y;
        }
        __syncthreads();
    }
    if (threadIdx.x < 64) {
        float2 s = red[threadIdx.x];
        int n = r1 - r0;
        float fn = (float)n;
        float denom = (float)(n > 0 ? n : 1);
        int d = 2 * threadIdx.x;
        pl[d]     = (ac[d] * s.x     + ac[DIM + d] * fn)     / denom;
        pl[d + 1] = (ac[d + 1] * s.y + ac[DIM + d + 1] * fn) / denom;
    }
    __syncthreads();
    if (threadIdx.x < 64) {
        int j = threadIdx.x;
        float hh = b1[j];
#pragma unroll
        for (int k = 0; k < DIM; ++k) hh = fmaf(pl[k], w1[k * 64 + j], hh);
        hh = fmaxf(hh, 0.f);
        float v = hh * w2[j];
#pragma unroll
        for (int o = 32; o > 0; o >>= 1) v += __shfl_down(v, o);
        if (j == 0) out[g] = v + b2[0];
    }
}

extern "C" void kernel_launch(void* const* d_in, const int* in_sizes, int n_in,
                              void* d_out, int out_size, void* d_ws, size_t ws_size,
                              hipStream_t stream) {
    const float* x      = (const float*)d_in[0];
    const int*   ei     = (const int*)d_in[1];
    const int*   batch  = (const int*)d_in[2];
    const float* Ws     = (const float*)d_in[3];
    const float* bs     = (const float*)d_in[4];
    const float* gammas = (const float*)d_in[5];
    const float* betas  = (const float*)d_in[6];
    const float* w1     = (const float*)d_in[7];
    const float* b1     = (const float*)d_in[8];
    const float* w2     = (const float*)d_in[9];
    const float* b2     = (const float*)d_in[10];
    float* out = (float*)d_out;

    char* p = (char*)d_ws;
    auto alloc = [&](size_t bytes) { void* r = (void*)p; p += (bytes + 255) & ~(size_t)255; return r; };
    int*    cnt      = (int*)alloc((size_t)N_NODES * 4);
    int*    off      = (int*)alloc((size_t)(N_NODES + 1) * 4);
    int*    rank     = (int*)alloc((size_t)N_EDGES * 4);
    int*    goff     = (int*)alloc((size_t)(N_GRAPHS + 1) * 4);
    int*    blocksum = (int*)alloc((size_t)(SCAN_NB + 1) * 4);
    int*    elist    = (int*)alloc((size_t)N_EDGES * 4);
    float*  dinv     = (float*)alloc((size_t)N_NODES * 4);
    __half* wt       = (__half*)alloc((size_t)3 * 2 * DIM * WTP * 2);
    __half* h16      = (__half*)alloc((size_t)N_NODES * DIM * 2);
    __half* v16      = (__half*)alloc((size_t)N_NODES * DIM * 2);
    float*  parts    = (float*)alloc((size_t)AGG_BLOCKS * 256 * 4);
    float*  ac       = (float*)alloc(256 * 4);

    hipMemsetAsync(cnt, 0, (size_t)N_NODES * 4, stream);

    k_count_edges<<<(N_EDGES + 255) / 256, 256, 0, stream>>>(ei, cnt, rank);
    k_scan_blk<<<SCAN_NB, 1024, 0, stream>>>(cnt, off, blocksum);
    k_scan_fix<<<SCAN_NB, 1024, 0, stream>>>(cnt, blocksum, off, dinv, batch, goff);
    k_fill_prepw<<<FILL_NB + PREPW_NB, 256, 0, stream>>>(ei, rank, off, elist, Ws, wt);

    for (int l = 0; l < 3; ++l) {
        if (l == 0)
            k_gemm_f32<<<GEMM_BLOCKS, 256, 0, stream>>>(x, wt, bs, h16);
        else
            k_gemm_f16<<<GEMM_BLOCKS, 256, 0, stream>>>(v16, wt + (size_t)l * 2 * DIM * WTP,
                                                        bs + (size_t)l * DIM, ac, h16);
        k_agg<<<AGG_BLOCKS, 1024, 0, stream>>>(h16, off, elist, dinv, v16, parts);
        k_stats<<<8, 1024, 0, stream>>>(parts, gammas + (size_t)l * DIM, betas + (size_t)l * DIM, ac);
    }
    k_poolmlp<<<N_GRAPHS, 1024, 0, stream>>>(v16, ac, goff, w1, b1, w2, b2, out);
}